// Round 1
// baseline (727.879 us; speedup 1.0000x reference)
//
#include <hip/hip_runtime.h>

#define TWO_PI_F 6.28318530717958647692f
#define SCL_F    0.02209708691207961f   // TEMP/SCALE/sqrt(128)

// ---------------------------------------------------------------------------
// Group-norm statistics: per (b, g) over 16384 rows x 32 channels.
// grid = (64 chunks, 32 groups), block = 256
// ---------------------------------------------------------------------------
__global__ __launch_bounds__(256) void gn_partial_k(const float* __restrict__ X,
                                                    float* __restrict__ partials)
{
    int t = threadIdx.x;
    int chunk = blockIdx.x;   // 0..63
    int grp = blockIdx.y;     // 0..31 = b*4+g
    int b = grp >> 2, g = grp & 3;
    const float* base = X + ((long)b * 16384 + (long)chunk * 256) * 128 + g * 32;
    float s = 0.f, ss = 0.f;
#pragma unroll
    for (int i = 0; i < 8; i++) {
        int rl = i * 32 + (t >> 3);
        int c4 = (t & 7) * 4;
        float4 v = *(const float4*)(base + (long)rl * 128 + c4);
        s  += v.x + v.y + v.z + v.w;
        ss += v.x * v.x + v.y * v.y + v.z * v.z + v.w * v.w;
    }
    __shared__ float r0[256], r1[256];
    r0[t] = s; r1[t] = ss;
    __syncthreads();
    for (int off = 128; off > 0; off >>= 1) {
        if (t < off) { r0[t] += r0[t + off]; r1[t] += r1[t + off]; }
        __syncthreads();
    }
    if (t == 0) {
        partials[(grp * 64 + chunk) * 2]     = r0[0];
        partials[(grp * 64 + chunk) * 2 + 1] = r1[0];
    }
}

__global__ void gn_final_k(const float* __restrict__ partials, float* __restrict__ stats)
{
    int grp = blockIdx.x, t = threadIdx.x;  // 32 blocks x 64 threads
    float s  = partials[(grp * 64 + t) * 2];
    float ss = partials[(grp * 64 + t) * 2 + 1];
    for (int off = 1; off < 64; off <<= 1) { s += __shfl_xor(s, off); ss += __shfl_xor(ss, off); }
    if (t == 0) {
        const float N = 524288.0f;
        float mu = s / N;
        float var = ss / N - mu * mu;
        stats[grp * 2]     = mu;
        stats[grp * 2 + 1] = 1.0f / sqrtf(var + 0.001f);
    }
}

// ---------------------------------------------------------------------------
// C[M,128] = act( gn(X) @ W + bias ), M=131072. grid=2048 (64 rows/block), block=256.
// thread (ty=t>>4, tx=t&15) computes rows ty*4..+3, cols {tx*4..+3, 64+tx*4..+3}
// ---------------------------------------------------------------------------
__global__ __launch_bounds__(256) void gemm128_k(const float* __restrict__ X,
                                                 const float* __restrict__ W,
                                                 const float* __restrict__ bias,
                                                 const float* __restrict__ stats,
                                                 float* __restrict__ C, int leaky)
{
    __shared__ float sX[64][132];
    __shared__ float sW[32][132];
    int t = threadIdx.x;
    long row0 = (long)blockIdx.x * 64;
    int bidx = (int)(row0 >> 14);  // batch (64 | 16384 so uniform per block)

    float muv[4], rsv[4];
#pragma unroll
    for (int g = 0; g < 4; g++) {
        if (stats) { muv[g] = stats[(bidx * 4 + g) * 2]; rsv[g] = stats[(bidx * 4 + g) * 2 + 1]; }
        else       { muv[g] = 0.f; rsv[g] = 1.f; }
    }
    // load + normalize X tile (64x128)
#pragma unroll
    for (int i = 0; i < 8; i++) {
        int flat = i * 256 + t;           // float4 index over 64x32
        int r = flat >> 5, cq = flat & 31;
        float4 v = *(const float4*)(X + (row0 + r) * 128 + cq * 4);
        int g = cq >> 3;
        float mu = muv[g], rs = rsv[g];
        float4 o; o.x = (v.x - mu) * rs; o.y = (v.y - mu) * rs;
        o.z = (v.z - mu) * rs; o.w = (v.w - mu) * rs;
        *(float4*)&sX[r][cq * 4] = o;
    }

    int ty = t >> 4, tx = t & 15;
    int ty4 = ty * 4, txa = tx * 4, txb = 64 + tx * 4;
    float acc[4][8];
#pragma unroll
    for (int i = 0; i < 4; i++)
#pragma unroll
        for (int j = 0; j < 8; j++) acc[i][j] = 0.f;

    for (int kt = 0; kt < 4; kt++) {
        int kt32 = kt * 32;
#pragma unroll
        for (int i = 0; i < 4; i++) {
            int flat = i * 256 + t;       // float4 index over 32x32
            int r = flat >> 5, cq = flat & 31;
            *(float4*)&sW[r][cq * 4] = *(const float4*)(W + (long)(kt32 + r) * 128 + cq * 4);
        }
        __syncthreads();
#pragma unroll
        for (int k = 0; k < 32; k += 4) {
            float4 xv[4];
#pragma unroll
            for (int i = 0; i < 4; i++) xv[i] = *(const float4*)&sX[ty4 + i][kt32 + k];
#pragma unroll
            for (int kk = 0; kk < 4; kk++) {
                float4 wa = *(const float4*)&sW[k + kk][txa];
                float4 wb = *(const float4*)&sW[k + kk][txb];
#pragma unroll
                for (int i = 0; i < 4; i++) {
                    float x = ((const float*)(xv + i))[kk];
                    acc[i][0] += x * wa.x; acc[i][1] += x * wa.y;
                    acc[i][2] += x * wa.z; acc[i][3] += x * wa.w;
                    acc[i][4] += x * wb.x; acc[i][5] += x * wb.y;
                    acc[i][6] += x * wb.z; acc[i][7] += x * wb.w;
                }
            }
        }
        __syncthreads();
    }

    float ba[8];
#pragma unroll
    for (int j = 0; j < 4; j++) {
        ba[j]     = bias ? bias[txa + j] : 0.f;
        ba[4 + j] = bias ? bias[txb + j] : 0.f;
    }
#pragma unroll
    for (int i = 0; i < 4; i++) {
        float v[8];
#pragma unroll
        for (int j = 0; j < 8; j++) {
            float x = acc[i][j] + ba[j];
            if (leaky) x = (x >= 0.f) ? x : 0.01f * x;
            v[j] = x;
        }
        long r = row0 + ty4 + i;
        float4 va; va.x = v[0]; va.y = v[1]; va.z = v[2]; va.w = v[3];
        float4 vb; vb.x = v[4]; vb.y = v[5]; vb.z = v[6]; vb.w = v[7];
        *(float4*)(C + r * 128 + txa) = va;
        *(float4*)(C + r * 128 + txb) = vb;
    }
}

// ---------------------------------------------------------------------------
// Per-window: q = gn2(qraw) -> write q; S = sq_dist(q,q); softmax; min-max -> af
// grid = 2048, block = 256
// ---------------------------------------------------------------------------
__global__ __launch_bounds__(256) void attn_k(const float* __restrict__ Qraw,
                                              const float* __restrict__ stats,
                                              float* __restrict__ outQ,
                                              float* __restrict__ outAF)
{
    __shared__ float sQ[64][132];
    __shared__ float sS[64][68];
    __shared__ float sN[64];
    int t = threadIdx.x, w = blockIdx.x;
    int bidx = w >> 8;
    float muv[4], rsv[4];
#pragma unroll
    for (int g = 0; g < 4; g++) {
        muv[g] = stats[(bidx * 4 + g) * 2];
        rsv[g] = stats[(bidx * 4 + g) * 2 + 1];
    }
    const float* Qw = Qraw + (long)w * 8192;
    float* oQ = outQ + (long)w * 8192;
#pragma unroll
    for (int i = 0; i < 8; i++) {
        int flat = i * 256 + t;
        int r = flat >> 5, cq = flat & 31;
        float4 v = *(const float4*)(Qw + r * 128 + cq * 4);
        int g = cq >> 3;
        float mu = muv[g], rs = rsv[g];
        float4 o; o.x = (v.x - mu) * rs; o.y = (v.y - mu) * rs;
        o.z = (v.z - mu) * rs; o.w = (v.w - mu) * rs;
        *(float4*)&sQ[r][cq * 4] = o;
        *(float4*)(oQ + r * 128 + cq * 4) = o;
    }
    __syncthreads();
    if (t < 64) {
        float s = 0.f;
#pragma unroll
        for (int k = 0; k < 128; k += 4) {
            float4 v = *(const float4*)&sQ[t][k];
            s += v.x * v.x + v.y * v.y + v.z * v.z + v.w * v.w;
        }
        sN[t] = s;
    }
    __syncthreads();
    int ty = t >> 4, tx = t & 15;
    int i0 = ty * 4, j0 = tx * 4;
    float acc[4][4];
#pragma unroll
    for (int a = 0; a < 4; a++)
#pragma unroll
        for (int bb = 0; bb < 4; bb++) acc[a][bb] = 0.f;
    for (int k = 0; k < 128; k += 4) {
        float4 qi[4], qj[4];
#pragma unroll
        for (int a = 0; a < 4; a++) qi[a] = *(const float4*)&sQ[i0 + a][k];
#pragma unroll
        for (int bb = 0; bb < 4; bb++) qj[bb] = *(const float4*)&sQ[j0 + bb][k];
#pragma unroll
        for (int a = 0; a < 4; a++)
#pragma unroll
            for (int bb = 0; bb < 4; bb++)
                acc[a][bb] += qi[a].x * qj[bb].x + qi[a].y * qj[bb].y
                            + qi[a].z * qj[bb].z + qi[a].w * qj[bb].w;
    }
#pragma unroll
    for (int a = 0; a < 4; a++)
#pragma unroll
        for (int bb = 0; bb < 4; bb++)
            sS[i0 + a][j0 + bb] = sN[i0 + a] + sN[j0 + bb] - 2.f * acc[a][bb];
    __syncthreads();
    int wv = t >> 6, lane = t & 63;
    for (int rr = 0; rr < 16; rr++) {
        int i = wv * 16 + rr;
        float l = -SCL_F * sS[i][lane];
        float mx = l;
        for (int off = 1; off < 64; off <<= 1) mx = fmaxf(mx, __shfl_xor(mx, off));
        float p = expf(l - mx);
        float sum = p;
        for (int off = 1; off < 64; off <<= 1) sum += __shfl_xor(sum, off);
        float af = p / sum;
        float amx = af, amn = af;
        for (int off = 1; off < 64; off <<= 1) {
            amx = fmaxf(amx, __shfl_xor(amx, off));
            amn = fminf(amn, __shfl_xor(amn, off));
        }
        outAF[(long)w * 4096 + i * 64 + lane] = (af - amn) / (amx - amn + 1e-8f);
    }
}

// ---------------------------------------------------------------------------
// Per-window clustering. grid = 2048, block = 256 (4 waves)
// ---------------------------------------------------------------------------
__global__ __launch_bounds__(256) void cluster_k(const float* __restrict__ AF,
                                                 const float* __restrict__ GEO,
                                                 float* __restrict__ oCLM,
                                                 float* __restrict__ oCLR,
                                                 float* __restrict__ oCOMP,
                                                 float* __restrict__ oGEO,
                                                 float* __restrict__ oSCM,
                                                 float* __restrict__ wCLMM)
{
    __shared__ float sAF[64][66];
    __shared__ float sD[64], sA[64], sI[64], sCx[64], sCy[64];
    __shared__ float sComp[64];
    __shared__ float sCLM[8][66];
    int t = threadIdx.x, w = blockIdx.x;
    const float* afw = AF + (long)w * 4096;
#pragma unroll
    for (int i = 0; i < 16; i++) {
        int flat = i * 256 + t;
        float v = afw[flat];
        v = fminf(fmaxf(v, 1e-5f), 0.99999f);
        sAF[flat >> 6][flat & 63] = v;
    }
    if (t < 64) {
        const float* g = GEO + ((long)w * 64 + t) * 6;
        sD[t] = g[0]; sA[t] = g[2]; sI[t] = g[3]; sCx[t] = g[4]; sCy[t] = g[5];
    }
    __syncthreads();
    int wv = t >> 6, k = t & 63;
    float dk = sD[k], ak = sA[k], ik = sI[k], xk = sCx[k], yk = sCy[k];

    // phase 1: per-row compactness (rows 0..63, 16 per wave)
    for (int rr = 0; rr < 16; rr++) {
        int q = wv * 16 + rr;
        float af = sAF[q][k];
        float d = af * dk, a = af * ak;
        float m = d * a;
        float dx = sCx[q] - xk, dy = sCy[q] - yk;
        float v0 = d * ik + m * (dx * dx + dy * dy);  // -> newiner
        float v1 = m * a;
        float suf = 0.f;
        for (int j = 0; j < 64; j++) {
            float dj = __shfl(d, j), aj = __shfl(a, j);
            if (dj > d || (dj == d && j > k)) suf += aj;
        }
        float v2 = 2.f * d * a * suf;
        for (int off = 1; off < 64; off <<= 1) {
            v0 += __shfl_xor(v0, off);
            v1 += __shfl_xor(v1, off);
            v2 += __shfl_xor(v2, off);
        }
        if (k == 0) sComp[q] = ((v1 + v2) / TWO_PI_F) / v0;
    }
    __syncthreads();

    // phase 2: greedy selection (wave 0 only)
    if (t < 64) {
        float sc = 1.0f;
        float compk = sComp[k];
        for (int c = 0; c < 7; c++) {
            float score = compk * sc;
            float mx = score;
            for (int off = 1; off < 64; off <<= 1) mx = fmaxf(mx, __shfl_xor(mx, off));
            unsigned long long bl = __ballot(score == mx);
            int idx = __ffsll(bl) - 1;   // first max (matches jnp.argmax)
            float rowk = sAF[idx][k];
            float clm = sc * rowk;
            sCLM[c][k] = clm;
            oCLM[(long)w * 512 + c * 64 + k] = clm;
            if (k == 0) oCLR[(long)w * 7 + c] = (float)idx;
            sc *= (1.0f - rowk);
        }
        sCLM[7][k] = sc;
        oCLM[(long)w * 512 + 448 + k] = sc;
        oSCM[(long)w * 64 + k] = sc;
    }
    __syncthreads();

    // phase 3: cluster aggregates + second compactness (8 rows, 2 per wave)
    for (int cc = 0; cc < 2; cc++) {
        int c = wv + cc * 4;
        float clm = sCLM[c][k];
        float cd = clm * dk, ca = clm * ak, cm = cd * ca;
        float r0 = cm, r1 = ca, r2 = cm * xk, r3 = cm * yk, r4 = clm;
        for (int off = 1; off < 64; off <<= 1) {
            r0 += __shfl_xor(r0, off); r1 += __shfl_xor(r1, off);
            r2 += __shfl_xor(r2, off); r3 += __shfl_xor(r3, off);
            r4 += __shfl_xor(r4, off);
        }
        float mass = r0, area = r1;
        float qx = r2 / (mass + 1e-8f), qy = r3 / (mass + 1e-8f);
        float densc = mass / (area + 1e-8f);
        wCLMM[(long)w * 512 + c * 64 + k] = clm / (r4 + 1e-8f);
        float dx = qx - xk, dy = qy - yk;
        float w0 = cd * ik + cm * (dx * dx + dy * dy);
        float w1 = cm * ca;
        float suf = 0.f;
        for (int j = 0; j < 64; j++) {
            float dj = __shfl(cd, j), aj = __shfl(ca, j);
            if (dj > cd || (dj == cd && j > k)) suf += aj;
        }
        float w2 = 2.f * cd * ca * suf;
        for (int off = 1; off < 64; off <<= 1) {
            w0 += __shfl_xor(w0, off); w1 += __shfl_xor(w1, off); w2 += __shfl_xor(w2, off);
        }
        if (k == 0) {
            oCOMP[(long)w * 8 + c] = ((w1 + w2) / TWO_PI_F) / w0;
            float* og = oGEO + (long)w * 48 + c * 6;
            og[0] = densc; og[1] = mass; og[2] = area; og[3] = w0; og[4] = qx; og[5] = qy;
        }
    }
}

// ---------------------------------------------------------------------------
// Per-window cl_f assembly:
// cl_f = t0 + (u@W2 + s_c*b2) + (t1@Wv)@Wfc + bfc
//   u  = cl_mm@h1, t1 = cl_mm@_f, t0 = t1*sigma + mu*s_c  (== cl_mm@in_f)
// grid = 2048, block = 256
// ---------------------------------------------------------------------------
__global__ __launch_bounds__(256) void final_k(const float* __restrict__ inF,
                                               const float* __restrict__ H1,
                                               const float* __restrict__ CLMM,
                                               const float* __restrict__ stats1,
                                               const float* __restrict__ W2,
                                               const float* __restrict__ b2,
                                               const float* __restrict__ Wv,
                                               const float* __restrict__ Wfc,
                                               const float* __restrict__ bfc,
                                               float* __restrict__ oCLF)
{
    __shared__ float sBuf[64][132];
    __shared__ float sMM[8][66];
    __shared__ float sU[8][132];
    __shared__ float sT1[8][132];
    __shared__ float sV[8][132];
    __shared__ float sSc[8];
    int t = threadIdx.x, w = blockIdx.x;
    int bidx = w >> 8;
#pragma unroll
    for (int i = 0; i < 2; i++) {
        int flat = i * 256 + t;
        sMM[flat >> 6][flat & 63] = CLMM[(long)w * 512 + flat];
    }
    const float* h1w = H1 + (long)w * 8192;
#pragma unroll
    for (int i = 0; i < 8; i++) {
        int flat = i * 256 + t;
        int r = flat >> 5, cq = flat & 31;
        *(float4*)&sBuf[r][cq * 4] = *(const float4*)(h1w + r * 128 + cq * 4);
    }
    __syncthreads();
    if (t < 8) {
        float s = 0.f;
        for (int k = 0; k < 64; k++) s += sMM[t][k];
        sSc[t] = s;
    }
    int ch = t & 127, ci0 = (t >> 7) * 4;
    float uacc[4] = {0.f, 0.f, 0.f, 0.f};
    for (int k = 0; k < 64; k++) {
        float hv = sBuf[k][ch];
#pragma unroll
        for (int i = 0; i < 4; i++) uacc[i] += sMM[ci0 + i][k] * hv;
    }
#pragma unroll
    for (int i = 0; i < 4; i++) sU[ci0 + i][ch] = uacc[i];
    __syncthreads();

    float muv[4], rsv[4];
#pragma unroll
    for (int g = 0; g < 4; g++) {
        muv[g] = stats1[(bidx * 4 + g) * 2];
        rsv[g] = stats1[(bidx * 4 + g) * 2 + 1];
    }
    const float* fw = inF + (long)w * 8192;
#pragma unroll
    for (int i = 0; i < 8; i++) {
        int flat = i * 256 + t;
        int r = flat >> 5, cq = flat & 31;
        float4 v = *(const float4*)(fw + r * 128 + cq * 4);
        int g = cq >> 3;
        float mu = muv[g], rs = rsv[g];
        float4 o; o.x = (v.x - mu) * rs; o.y = (v.y - mu) * rs;
        o.z = (v.z - mu) * rs; o.w = (v.w - mu) * rs;
        *(float4*)&sBuf[r][cq * 4] = o;
    }
    __syncthreads();
    float t1acc[4] = {0.f, 0.f, 0.f, 0.f};
    for (int k = 0; k < 64; k++) {
        float fv = sBuf[k][ch];
#pragma unroll
        for (int i = 0; i < 4; i++) t1acc[i] += sMM[ci0 + i][k] * fv;
    }
#pragma unroll
    for (int i = 0; i < 4; i++) sT1[ci0 + i][ch] = t1acc[i];
    int g = ch >> 5;
    float sigma = 1.0f / rsv[g];
    float mu = muv[g];
    float b2v = b2[ch], bfcv = bfc[ch];
    float part[4];
#pragma unroll
    for (int i = 0; i < 4; i++)
        part[i] = t1acc[i] * sigma + sSc[ci0 + i] * (mu + b2v) + bfcv;
    __syncthreads();
    float vacc[4] = {0.f, 0.f, 0.f, 0.f};
    for (int k = 0; k < 128; k++) {
        float w2v = W2[k * 128 + ch];
        float wvv = Wv[k * 128 + ch];
#pragma unroll
        for (int i = 0; i < 4; i++) {
            part[i] += sU[ci0 + i][k] * w2v;
            vacc[i] += sT1[ci0 + i][k] * wvv;
        }
    }
#pragma unroll
    for (int i = 0; i < 4; i++) sV[ci0 + i][ch] = vacc[i];
    __syncthreads();
    for (int k = 0; k < 128; k++) {
        float wf = Wfc[k * 128 + ch];
#pragma unroll
        for (int i = 0; i < 4; i++) part[i] += sV[ci0 + i][k] * wf;
    }
#pragma unroll
    for (int i = 0; i < 4; i++)
        oCLF[(long)w * 1024 + (ci0 + i) * 128 + ch] = part[i];
}

// ---------------------------------------------------------------------------
extern "C" void kernel_launch(void* const* d_in, const int* in_sizes, int n_in,
                              void* d_out, int out_size, void* d_ws, size_t ws_size,
                              hipStream_t stream)
{
    (void)in_sizes; (void)n_in; (void)out_size; (void)ws_size;
    const float* in_f   = (const float*)d_in[0];
    const float* in_geo = (const float*)d_in[1];
    const float* W1  = (const float*)d_in[2];
    const float* b1  = (const float*)d_in[3];
    const float* W2  = (const float*)d_in[4];
    const float* b2  = (const float*)d_in[5];
    const float* Wfc = (const float*)d_in[6];
    const float* bfc = (const float*)d_in[7];
    const float* Wq  = (const float*)d_in[8];
    const float* Wv  = (const float*)d_in[9];
    float* out = (float*)d_out;
    float* ws  = (float*)d_ws;

    // workspace layout (floats): qraw/h1 shared buffer, cl_mm, partials, stats
    float* qh     = ws;                   // 16,777,216
    float* clmm   = ws + 16777216;        //  1,048,576
    float* part   = ws + 17825792;        //  4,096
    float* stats1 = ws + 17829888;        //  64
    float* stats2 = ws + 17829952;        //  64

    // output layout (floats)
    float* o_clf  = out;                  // (8,256,8,128)
    float* o_clm  = out + 2097152;        // (8,256,8,64)
    float* o_geo  = out + 3145728;        // (8,256,8,6)
    float* o_clr  = out + 3244032;        // (8,256,7,1)
    float* o_comp = out + 3258368;        // (8,256,8,1)
    float* o_af   = out + 3274752;        // (8,256,64,64)
    float* o_scm  = out + 11663360;       // (8,256,1,64)
    float* o_q    = out + 11794432;       // (8,256,64,128)

    dim3 gpart(64, 32);
    gn_partial_k<<<gpart, 256, 0, stream>>>(in_f, part);
    gn_final_k<<<32, 64, 0, stream>>>(part, stats1);
    // qraw = gn(in_f) @ Wq
    gemm128_k<<<2048, 256, 0, stream>>>(in_f, Wq, nullptr, stats1, qh, 0);
    gn_partial_k<<<gpart, 256, 0, stream>>>(qh, part);
    gn_final_k<<<32, 64, 0, stream>>>(part, stats2);
    // q + af
    attn_k<<<2048, 256, 0, stream>>>(qh, stats2, o_q, o_af);
    // h1 = leaky(gn(in_f) @ W1 + b1)  (reuses qraw buffer; attn already consumed it)
    gemm128_k<<<2048, 256, 0, stream>>>(in_f, W1, b1, stats1, qh, 1);
    // clustering
    cluster_k<<<2048, 256, 0, stream>>>(o_af, in_geo, o_clm, o_clr, o_comp, o_geo, o_scm, clmm);
    // cl_f assembly
    final_k<<<2048, 256, 0, stream>>>(in_f, qh, clmm, stats1, W2, b2, Wv, Wfc, bfc, o_clf);
}

// Round 2
// 549.334 us; speedup vs baseline: 1.3250x; 1.3250x over previous
//
#include <hip/hip_runtime.h>

#define TWO_PI_F 6.28318530717958647692f
#define SCL_F    0.02209708691207961f   // TEMP/SCALE/sqrt(128)

// ---------------------------------------------------------------------------
// Group-norm statistics: per (b, g) over 16384 rows x 32 channels.
// grid = (64 chunks, 32 groups), block = 256
// ---------------------------------------------------------------------------
__global__ __launch_bounds__(256) void gn_partial_k(const float* __restrict__ X,
                                                    float* __restrict__ partials)
{
    int t = threadIdx.x;
    int chunk = blockIdx.x;   // 0..63
    int grp = blockIdx.y;     // 0..31 = b*4+g
    int b = grp >> 2, g = grp & 3;
    const float* base = X + ((long)b * 16384 + (long)chunk * 256) * 128 + g * 32;
    float s = 0.f, ss = 0.f;
#pragma unroll
    for (int i = 0; i < 8; i++) {
        int rl = i * 32 + (t >> 3);
        int c4 = (t & 7) * 4;
        float4 v = *(const float4*)(base + (long)rl * 128 + c4);
        s  += v.x + v.y + v.z + v.w;
        ss += v.x * v.x + v.y * v.y + v.z * v.z + v.w * v.w;
    }
    __shared__ float r0[256], r1[256];
    r0[t] = s; r1[t] = ss;
    __syncthreads();
    for (int off = 128; off > 0; off >>= 1) {
        if (t < off) { r0[t] += r0[t + off]; r1[t] += r1[t + off]; }
        __syncthreads();
    }
    if (t == 0) {
        partials[(grp * 64 + chunk) * 2]     = r0[0];
        partials[(grp * 64 + chunk) * 2 + 1] = r1[0];
    }
}

__global__ void gn_final_k(const float* __restrict__ partials, float* __restrict__ stats)
{
    int grp = blockIdx.x, t = threadIdx.x;  // 32 blocks x 64 threads
    float s  = partials[(grp * 64 + t) * 2];
    float ss = partials[(grp * 64 + t) * 2 + 1];
    for (int off = 1; off < 64; off <<= 1) { s += __shfl_xor(s, off); ss += __shfl_xor(ss, off); }
    if (t == 0) {
        const float N = 524288.0f;
        float mu = s / N;
        float var = ss / N - mu * mu;
        stats[grp * 2]     = mu;
        stats[grp * 2 + 1] = 1.0f / sqrtf(var + 0.001f);
    }
}

// ---------------------------------------------------------------------------
// C[M,128] = act( gn(X) @ W + bias ), M=131072. grid=2048 (64 rows/block), block=256.
// ---------------------------------------------------------------------------
__global__ __launch_bounds__(256) void gemm128_k(const float* __restrict__ X,
                                                 const float* __restrict__ W,
                                                 const float* __restrict__ bias,
                                                 const float* __restrict__ stats,
                                                 float* __restrict__ C, int leaky)
{
    __shared__ float sX[64][132];
    __shared__ float sW[32][132];
    int t = threadIdx.x;
    long row0 = (long)blockIdx.x * 64;
    int bidx = (int)(row0 >> 14);  // batch (64 | 16384 so uniform per block)

    float muv[4], rsv[4];
#pragma unroll
    for (int g = 0; g < 4; g++) {
        if (stats) { muv[g] = stats[(bidx * 4 + g) * 2]; rsv[g] = stats[(bidx * 4 + g) * 2 + 1]; }
        else       { muv[g] = 0.f; rsv[g] = 1.f; }
    }
#pragma unroll
    for (int i = 0; i < 8; i++) {
        int flat = i * 256 + t;           // float4 index over 64x32
        int r = flat >> 5, cq = flat & 31;
        float4 v = *(const float4*)(X + (row0 + r) * 128 + cq * 4);
        int g = cq >> 3;
        float mu = muv[g], rs = rsv[g];
        float4 o; o.x = (v.x - mu) * rs; o.y = (v.y - mu) * rs;
        o.z = (v.z - mu) * rs; o.w = (v.w - mu) * rs;
        *(float4*)&sX[r][cq * 4] = o;
    }

    int ty = t >> 4, tx = t & 15;
    int ty4 = ty * 4, txa = tx * 4, txb = 64 + tx * 4;
    float acc[4][8];
#pragma unroll
    for (int i = 0; i < 4; i++)
#pragma unroll
        for (int j = 0; j < 8; j++) acc[i][j] = 0.f;

    for (int kt = 0; kt < 4; kt++) {
        int kt32 = kt * 32;
#pragma unroll
        for (int i = 0; i < 4; i++) {
            int flat = i * 256 + t;       // float4 index over 32x32
            int r = flat >> 5, cq = flat & 31;
            *(float4*)&sW[r][cq * 4] = *(const float4*)(W + (long)(kt32 + r) * 128 + cq * 4);
        }
        __syncthreads();
#pragma unroll
        for (int k = 0; k < 32; k += 4) {
            float4 xv[4];
#pragma unroll
            for (int i = 0; i < 4; i++) xv[i] = *(const float4*)&sX[ty4 + i][kt32 + k];
#pragma unroll
            for (int kk = 0; kk < 4; kk++) {
                float4 wa = *(const float4*)&sW[k + kk][txa];
                float4 wb = *(const float4*)&sW[k + kk][txb];
#pragma unroll
                for (int i = 0; i < 4; i++) {
                    float x = ((const float*)(xv + i))[kk];
                    acc[i][0] += x * wa.x; acc[i][1] += x * wa.y;
                    acc[i][2] += x * wa.z; acc[i][3] += x * wa.w;
                    acc[i][4] += x * wb.x; acc[i][5] += x * wb.y;
                    acc[i][6] += x * wb.z; acc[i][7] += x * wb.w;
                }
            }
        }
        __syncthreads();
    }

    float ba[8];
#pragma unroll
    for (int j = 0; j < 4; j++) {
        ba[j]     = bias ? bias[txa + j] : 0.f;
        ba[4 + j] = bias ? bias[txb + j] : 0.f;
    }
#pragma unroll
    for (int i = 0; i < 4; i++) {
        float v[8];
#pragma unroll
        for (int j = 0; j < 8; j++) {
            float x = acc[i][j] + ba[j];
            if (leaky) x = (x >= 0.f) ? x : 0.01f * x;
            v[j] = x;
        }
        long r = row0 + ty4 + i;
        float4 va; va.x = v[0]; va.y = v[1]; va.z = v[2]; va.w = v[3];
        float4 vb; vb.x = v[4]; vb.y = v[5]; vb.z = v[6]; vb.w = v[7];
        *(float4*)(C + r * 128 + txa) = va;
        *(float4*)(C + r * 128 + txb) = vb;
    }
}

// ---------------------------------------------------------------------------
// Per-window: q = gn2(qraw) -> write q; S = sq_dist(q,q); softmax; min-max -> af
// grid = 2048, block = 256
// ---------------------------------------------------------------------------
__global__ __launch_bounds__(256) void attn_k(const float* __restrict__ Qraw,
                                              const float* __restrict__ stats,
                                              float* __restrict__ outQ,
                                              float* __restrict__ outAF)
{
    __shared__ float sQ[64][132];
    __shared__ float sS[64][68];
    __shared__ float sN[64];
    int t = threadIdx.x, w = blockIdx.x;
    int bidx = w >> 8;
    float muv[4], rsv[4];
#pragma unroll
    for (int g = 0; g < 4; g++) {
        muv[g] = stats[(bidx * 4 + g) * 2];
        rsv[g] = stats[(bidx * 4 + g) * 2 + 1];
    }
    const float* Qw = Qraw + (long)w * 8192;
    float* oQ = outQ + (long)w * 8192;
#pragma unroll
    for (int i = 0; i < 8; i++) {
        int flat = i * 256 + t;
        int r = flat >> 5, cq = flat & 31;
        float4 v = *(const float4*)(Qw + r * 128 + cq * 4);
        int g = cq >> 3;
        float mu = muv[g], rs = rsv[g];
        float4 o; o.x = (v.x - mu) * rs; o.y = (v.y - mu) * rs;
        o.z = (v.z - mu) * rs; o.w = (v.w - mu) * rs;
        *(float4*)&sQ[r][cq * 4] = o;
        *(float4*)(oQ + r * 128 + cq * 4) = o;
    }
    __syncthreads();
    if (t < 64) {
        float s = 0.f;
#pragma unroll
        for (int k = 0; k < 128; k += 4) {
            float4 v = *(const float4*)&sQ[t][k];
            s += v.x * v.x + v.y * v.y + v.z * v.z + v.w * v.w;
        }
        sN[t] = s;
    }
    __syncthreads();
    int ty = t >> 4, tx = t & 15;
    int i0 = ty * 4, j0 = tx * 4;
    float acc[4][4];
#pragma unroll
    for (int a = 0; a < 4; a++)
#pragma unroll
        for (int bb = 0; bb < 4; bb++) acc[a][bb] = 0.f;
    for (int k = 0; k < 128; k += 4) {
        float4 qi[4], qj[4];
#pragma unroll
        for (int a = 0; a < 4; a++) qi[a] = *(const float4*)&sQ[i0 + a][k];
#pragma unroll
        for (int bb = 0; bb < 4; bb++) qj[bb] = *(const float4*)&sQ[j0 + bb][k];
#pragma unroll
        for (int a = 0; a < 4; a++)
#pragma unroll
            for (int bb = 0; bb < 4; bb++)
                acc[a][bb] += qi[a].x * qj[bb].x + qi[a].y * qj[bb].y
                            + qi[a].z * qj[bb].z + qi[a].w * qj[bb].w;
    }
#pragma unroll
    for (int a = 0; a < 4; a++)
#pragma unroll
        for (int bb = 0; bb < 4; bb++)
            sS[i0 + a][j0 + bb] = sN[i0 + a] + sN[j0 + bb] - 2.f * acc[a][bb];
    __syncthreads();
    int wv = t >> 6, lane = t & 63;
    for (int rr = 0; rr < 16; rr++) {
        int i = wv * 16 + rr;
        float l = -SCL_F * sS[i][lane];
        float mx = l;
        for (int off = 1; off < 64; off <<= 1) mx = fmaxf(mx, __shfl_xor(mx, off));
        float p = expf(l - mx);
        float sum = p;
        for (int off = 1; off < 64; off <<= 1) sum += __shfl_xor(sum, off);
        float af = p / sum;
        float amx = af, amn = af;
        for (int off = 1; off < 64; off <<= 1) {
            amx = fmaxf(amx, __shfl_xor(amx, off));
            amn = fminf(amn, __shfl_xor(amn, off));
        }
        outAF[(long)w * 4096 + i * 64 + lane] = (af - amn) / (amx - amn + 1e-8f);
    }
}

// ---------------------------------------------------------------------------
// Per-window clustering, DS-minimized rewrite.
//   Key identity: min_pair_tril_sum(d,a) == 2 * sum_{j<k} a_j a_k min(d_j,d_k)
//   (tie-break is value-irrelevant when d_j == d_k), so no sort order needed.
//   Phase 1 transposed: lane = row q; pair (j,k) loop split over waves by k%4.
//   All LDS strides are 65 (odd) -> (q + j) % 32 bank mapping, conflict-free;
//   per-j uniform reads are same-address broadcasts.
// grid = 2048, block = 256
// ---------------------------------------------------------------------------
__global__ __launch_bounds__(256) void cluster_k(const float* __restrict__ AF,
                                                 const float* __restrict__ GEO,
                                                 float* __restrict__ oCLM,
                                                 float* __restrict__ oCLR,
                                                 float* __restrict__ oCOMP,
                                                 float* __restrict__ oGEO,
                                                 float* __restrict__ oSCM,
                                                 float* __restrict__ wCLMM)
{
    __shared__ float  sAF[64 * 65];   // clamped af, stride 65
    __shared__ float2 gDA[64];        // {dens, area} per k
    __shared__ float4 gIXY[64];       // {iner, x, y, 0} per k
    __shared__ float  sPart[4 * 64 * 3]; // per-wave partials (v0,v1,S) per row
    __shared__ float  sComp[64];
    __shared__ float  sCLM[8 * 65];   // cluster masses, stride 65

    int t = threadIdx.x, w = blockIdx.x;
    int wv = t >> 6, lane = t & 63;
    const float* afw = AF + (long)w * 4096;

    // ---- stage af (clamped) + geo into LDS ----
#pragma unroll
    for (int i = 0; i < 4; i++) {
        int f4 = i * 256 + t;             // float4 index over 64x16
        float4 v = *(const float4*)(afw + f4 * 4);
        int r = f4 >> 4, c0 = (f4 & 15) * 4;
        float* dst = &sAF[r * 65 + c0];
        dst[0] = fminf(fmaxf(v.x, 1e-5f), 0.99999f);
        dst[1] = fminf(fmaxf(v.y, 1e-5f), 0.99999f);
        dst[2] = fminf(fmaxf(v.z, 1e-5f), 0.99999f);
        dst[3] = fminf(fmaxf(v.w, 1e-5f), 0.99999f);
    }
    if (t < 64) {
        const float* g = GEO + ((long)w * 64 + t) * 6;
        float2 da; da.x = g[0]; da.y = g[2];
        gDA[t] = da;
        float4 ix; ix.x = g[3]; ix.y = g[4]; ix.z = g[5]; ix.w = 0.f;
        gIXY[t] = ix;
    }
    __syncthreads();

    // ---- phase 1 (transposed): lane owns row q; wave wv handles k = 4*kk+wv ----
    {
        int q = lane;
        const float* afrow = &sAF[q * 65];
        float xq = gIXY[q].y, yq = gIXY[q].z;
        float v0 = 0.f, v1 = 0.f, S = 0.f;
        for (int kk = 0; kk < 16; kk++) {
            int kc = kk * 4 + wv;                 // wave-uniform
            float afk = afrow[kc];
            float2 dak = gDA[kc];                 // broadcast
            float4 ixk = gIXY[kc];                // broadcast
            float dk = afk * dak.x, ak = afk * dak.y;
            float mk = dk * ak;
            float dx = xq - ixk.y, dy = yq - ixk.z;
            v0 += dk * ixk.x + mk * (dx * dx + dy * dy);
            v1 += mk * ak;
            // pair partial: j < kc  (wave-uniform trip count)
            float T0 = 0.f, T1 = 0.f;
            int j = 0;
            for (; j + 1 < kc; j += 2) {
                float afj0 = afrow[j];
                float2 daj0 = gDA[j];
                float afj1 = afrow[j + 1];
                float2 daj1 = gDA[j + 1];
                T0 = fmaf(afj0 * daj0.y, fminf(afj0 * daj0.x, dk), T0);
                T1 = fmaf(afj1 * daj1.y, fminf(afj1 * daj1.x, dk), T1);
            }
            if (j < kc) {
                float afj = afrow[j];
                float2 daj = gDA[j];
                T0 = fmaf(afj * daj.y, fminf(afj * daj.x, dk), T0);
            }
            S = fmaf(ak, T0 + T1, S);
        }
        float* p = &sPart[(wv * 64 + q) * 3];
        p[0] = v0; p[1] = v1; p[2] = S;
    }
    __syncthreads();

    // ---- phase 1 combine + phase 2 greedy (wave 0 only) ----
    if (t < 64) {
        int k = lane;
        float c0 = 0.f, c1 = 0.f, c2 = 0.f;
#pragma unroll
        for (int u = 0; u < 4; u++) {
            const float* p = &sPart[(u * 64 + k) * 3];
            c0 += p[0]; c1 += p[1]; c2 += p[2];
        }
        float compk = ((c1 + 2.f * c2) / TWO_PI_F) / c0;

        float sc = 1.0f;
        for (int c = 0; c < 7; c++) {
            float score = compk * sc;
            float mx = score;
            for (int off = 1; off < 64; off <<= 1) mx = fmaxf(mx, __shfl_xor(mx, off));
            unsigned long long bl = __ballot(score == mx);
            int idx = __ffsll(bl) - 1;            // first max (matches jnp.argmax)
            float rowk = sAF[idx * 65 + k];
            float clm = sc * rowk;
            sCLM[c * 65 + k] = clm;
            oCLM[(long)w * 512 + c * 64 + k] = clm;
            if (k == 0) oCLR[(long)w * 7 + c] = (float)idx;
            sc *= (1.0f - rowk);
        }
        sCLM[7 * 65 + k] = sc;
        oCLM[(long)w * 512 + 448 + k] = sc;
        oSCM[(long)w * 64 + k] = sc;
    }
    __syncthreads();

    // ---- phase 3: cluster aggregates + second compactness (2 rows/wave) ----
    {
        int k = lane;
        float2 dak = gDA[k];
        float4 ixk = gIXY[k];
        float dkD = dak.x, akA = dak.y, ik = ixk.x, xk = ixk.y, yk = ixk.z;
        for (int cc = 0; cc < 2; cc++) {
            int c = wv + cc * 4;
            float clm = sCLM[c * 65 + k];
            float cd = clm * dkD, ca = clm * akA;
            float cm = cd * ca;
            // T_k = sum_j ca_j * min(cd_j, cd_k)   (includes j==k; corrected below)
            float T0 = 0.f, T1 = 0.f;
            const float* clrow = &sCLM[c * 65];
#pragma unroll 4
            for (int j = 0; j < 64; j += 2) {
                float cj0 = clrow[j];                 // broadcast
                float2 dj0 = gDA[j];                  // broadcast
                float cj1 = clrow[j + 1];
                float2 dj1 = gDA[j + 1];
                T0 = fmaf(cj0 * dj0.y, fminf(cj0 * dj0.x, cd), T0);
                T1 = fmaf(cj1 * dj1.y, fminf(cj1 * dj1.x, cd), T1);
            }
            float spart = ca * (T0 + T1 - ca * cd);   // exclude self term
            float r0 = cm, r1 = ca, r2 = cm * xk, r3 = cm * yk, r4 = clm;
            float r5 = cm * ca, r6 = spart;
            for (int off = 1; off < 64; off <<= 1) {
                r0 += __shfl_xor(r0, off); r1 += __shfl_xor(r1, off);
                r2 += __shfl_xor(r2, off); r3 += __shfl_xor(r3, off);
                r4 += __shfl_xor(r4, off); r5 += __shfl_xor(r5, off);
                r6 += __shfl_xor(r6, off);
            }
            float mass = r0, area = r1;
            float qx = r2 / (mass + 1e-8f), qy = r3 / (mass + 1e-8f);
            wCLMM[(long)w * 512 + c * 64 + k] = clm / (r4 + 1e-8f);
            float dx = qx - xk, dy = qy - yk;
            float w0 = cd * ik + cm * (dx * dx + dy * dy);
            for (int off = 1; off < 64; off <<= 1) w0 += __shfl_xor(w0, off);
            if (k == 0) {
                oCOMP[(long)w * 8 + c] = ((r5 + r6) / TWO_PI_F) / w0;
                float* og = oGEO + (long)w * 48 + c * 6;
                og[0] = mass / (area + 1e-8f); og[1] = mass; og[2] = area;
                og[3] = w0; og[4] = qx; og[5] = qy;
            }
        }
    }
}

// ---------------------------------------------------------------------------
// Per-window cl_f assembly:
// cl_f = t0 + (u@W2 + s_c*b2) + (t1@Wv)@Wfc + bfc
//   u  = cl_mm@h1, t1 = cl_mm@_f, t0 = t1*sigma + mu*s_c  (== cl_mm@in_f)
// grid = 2048, block = 256
// ---------------------------------------------------------------------------
__global__ __launch_bounds__(256) void final_k(const float* __restrict__ inF,
                                               const float* __restrict__ H1,
                                               const float* __restrict__ CLMM,
                                               const float* __restrict__ stats1,
                                               const float* __restrict__ W2,
                                               const float* __restrict__ b2,
                                               const float* __restrict__ Wv,
                                               const float* __restrict__ Wfc,
                                               const float* __restrict__ bfc,
                                               float* __restrict__ oCLF)
{
    __shared__ float sBuf[64][132];
    __shared__ float sMM[8][66];
    __shared__ float sU[8][132];
    __shared__ float sT1[8][132];
    __shared__ float sV[8][132];
    __shared__ float sSc[8];
    int t = threadIdx.x, w = blockIdx.x;
    int bidx = w >> 8;
#pragma unroll
    for (int i = 0; i < 2; i++) {
        int flat = i * 256 + t;
        sMM[flat >> 6][flat & 63] = CLMM[(long)w * 512 + flat];
    }
    const float* h1w = H1 + (long)w * 8192;
#pragma unroll
    for (int i = 0; i < 8; i++) {
        int flat = i * 256 + t;
        int r = flat >> 5, cq = flat & 31;
        *(float4*)&sBuf[r][cq * 4] = *(const float4*)(h1w + r * 128 + cq * 4);
    }
    __syncthreads();
    if (t < 8) {
        float s = 0.f;
        for (int k = 0; k < 64; k++) s += sMM[t][k];
        sSc[t] = s;
    }
    int ch = t & 127, ci0 = (t >> 7) * 4;
    float uacc[4] = {0.f, 0.f, 0.f, 0.f};
    for (int k = 0; k < 64; k++) {
        float hv = sBuf[k][ch];
#pragma unroll
        for (int i = 0; i < 4; i++) uacc[i] += sMM[ci0 + i][k] * hv;
    }
#pragma unroll
    for (int i = 0; i < 4; i++) sU[ci0 + i][ch] = uacc[i];
    __syncthreads();

    float muv[4], rsv[4];
#pragma unroll
    for (int g = 0; g < 4; g++) {
        muv[g] = stats1[(bidx * 4 + g) * 2];
        rsv[g] = stats1[(bidx * 4 + g) * 2 + 1];
    }
    const float* fw = inF + (long)w * 8192;
#pragma unroll
    for (int i = 0; i < 8; i++) {
        int flat = i * 256 + t;
        int r = flat >> 5, cq = flat & 31;
        float4 v = *(const float4*)(fw + r * 128 + cq * 4);
        int g = cq >> 3;
        float mu = muv[g], rs = rsv[g];
        float4 o; o.x = (v.x - mu) * rs; o.y = (v.y - mu) * rs;
        o.z = (v.z - mu) * rs; o.w = (v.w - mu) * rs;
        *(float4*)&sBuf[r][cq * 4] = o;
    }
    __syncthreads();
    float t1acc[4] = {0.f, 0.f, 0.f, 0.f};
    for (int k = 0; k < 64; k++) {
        float fv = sBuf[k][ch];
#pragma unroll
        for (int i = 0; i < 4; i++) t1acc[i] += sMM[ci0 + i][k] * fv;
    }
#pragma unroll
    for (int i = 0; i < 4; i++) sT1[ci0 + i][ch] = t1acc[i];
    int g = ch >> 5;
    float sigma = 1.0f / rsv[g];
    float mu = muv[g];
    float b2v = b2[ch], bfcv = bfc[ch];
    float part[4];
#pragma unroll
    for (int i = 0; i < 4; i++)
        part[i] = t1acc[i] * sigma + sSc[ci0 + i] * (mu + b2v) + bfcv;
    __syncthreads();
    float vacc[4] = {0.f, 0.f, 0.f, 0.f};
    for (int k = 0; k < 128; k++) {
        float w2v = W2[k * 128 + ch];
        float wvv = Wv[k * 128 + ch];
#pragma unroll
        for (int i = 0; i < 4; i++) {
            part[i] += sU[ci0 + i][k] * w2v;
            vacc[i] += sT1[ci0 + i][k] * wvv;
        }
    }
#pragma unroll
    for (int i = 0; i < 4; i++) sV[ci0 + i][ch] = vacc[i];
    __syncthreads();
    for (int k = 0; k < 128; k++) {
        float wf = Wfc[k * 128 + ch];
#pragma unroll
        for (int i = 0; i < 4; i++) part[i] += sV[ci0 + i][k] * wf;
    }
#pragma unroll
    for (int i = 0; i < 4; i++)
        oCLF[(long)w * 1024 + (ci0 + i) * 128 + ch] = part[i];
}

// ---------------------------------------------------------------------------
extern "C" void kernel_launch(void* const* d_in, const int* in_sizes, int n_in,
                              void* d_out, int out_size, void* d_ws, size_t ws_size,
                              hipStream_t stream)
{
    (void)in_sizes; (void)n_in; (void)out_size; (void)ws_size;
    const float* in_f   = (const float*)d_in[0];
    const float* in_geo = (const float*)d_in[1];
    const float* W1  = (const float*)d_in[2];
    const float* b1  = (const float*)d_in[3];
    const float* W2  = (const float*)d_in[4];
    const float* b2  = (const float*)d_in[5];
    const float* Wfc = (const float*)d_in[6];
    const float* bfc = (const float*)d_in[7];
    const float* Wq  = (const float*)d_in[8];
    const float* Wv  = (const float*)d_in[9];
    float* out = (float*)d_out;
    float* ws  = (float*)d_ws;

    // workspace layout (floats): qraw/h1 shared buffer, cl_mm, partials, stats
    float* qh     = ws;                   // 16,777,216
    float* clmm   = ws + 16777216;        //  1,048,576
    float* part   = ws + 17825792;        //  4,096
    float* stats1 = ws + 17829888;        //  64
    float* stats2 = ws + 17829952;        //  64

    // output layout (floats)
    float* o_clf  = out;                  // (8,256,8,128)
    float* o_clm  = out + 2097152;        // (8,256,8,64)
    float* o_geo  = out + 3145728;        // (8,256,8,6)
    float* o_clr  = out + 3244032;        // (8,256,7,1)
    float* o_comp = out + 3258368;        // (8,256,8,1)
    float* o_af   = out + 3274752;        // (8,256,64,64)
    float* o_scm  = out + 11663360;       // (8,256,1,64)
    float* o_q    = out + 11794432;       // (8,256,64,128)

    dim3 gpart(64, 32);
    gn_partial_k<<<gpart, 256, 0, stream>>>(in_f, part);
    gn_final_k<<<32, 64, 0, stream>>>(part, stats1);
    // qraw = gn(in_f) @ Wq
    gemm128_k<<<2048, 256, 0, stream>>>(in_f, Wq, nullptr, stats1, qh, 0);
    gn_partial_k<<<gpart, 256, 0, stream>>>(qh, part);
    gn_final_k<<<32, 64, 0, stream>>>(part, stats2);
    // q + af
    attn_k<<<2048, 256, 0, stream>>>(qh, stats2, o_q, o_af);
    // h1 = leaky(gn(in_f) @ W1 + b1)  (reuses qraw buffer; attn already consumed it)
    gemm128_k<<<2048, 256, 0, stream>>>(in_f, W1, b1, stats1, qh, 1);
    // clustering
    cluster_k<<<2048, 256, 0, stream>>>(o_af, in_geo, o_clm, o_clr, o_comp, o_geo, o_scm, clmm);
    // cl_f assembly
    final_k<<<2048, 256, 0, stream>>>(in_f, qh, clmm, stats1, W2, b2, Wv, Wfc, bfc, o_clf);
}

// Round 3
// 497.401 us; speedup vs baseline: 1.4634x; 1.1044x over previous
//
#include <hip/hip_runtime.h>

#define TWO_PI_F 6.28318530717958647692f
#define SCL_F    0.02209708691207961f   // TEMP/SCALE/sqrt(128)

__device__ __forceinline__ float rlane(float v, int l) {
    return __uint_as_float((unsigned)__builtin_amdgcn_readlane((int)__float_as_uint(v), l));
}

// ---------------------------------------------------------------------------
// Group-norm partial stats for in_f: per (b,g) over 16384 rows x 32 ch.
// grid=(64,32), block=256
// ---------------------------------------------------------------------------
__global__ __launch_bounds__(256) void gn_partial_k(const float* __restrict__ X,
                                                    float* __restrict__ partials)
{
    int t = threadIdx.x;
    int chunk = blockIdx.x;
    int grp = blockIdx.y;          // b*4+g
    int b = grp >> 2, g = grp & 3;
    const float* base = X + ((long)b * 16384 + (long)chunk * 256) * 128 + g * 32;
    float s = 0.f, ss = 0.f;
#pragma unroll
    for (int i = 0; i < 8; i++) {
        int rl_ = i * 32 + (t >> 3);
        int c4 = (t & 7) * 4;
        float4 v = *(const float4*)(base + (long)rl_ * 128 + c4);
        s  += v.x + v.y + v.z + v.w;
        ss += v.x * v.x + v.y * v.y + v.z * v.z + v.w * v.w;
    }
    __shared__ float r0[256], r1[256];
    r0[t] = s; r1[t] = ss;
    __syncthreads();
    for (int off = 128; off > 0; off >>= 1) {
        if (t < off) { r0[t] += r0[t + off]; r1[t] += r1[t + off]; }
        __syncthreads();
    }
    if (t == 0) {
        partials[(grp * 64 + chunk) * 2]     = r0[0];
        partials[(grp * 64 + chunk) * 2 + 1] = r1[0];
    }
}

// grid=32, block=64; nblk partials per group
__global__ void gn_final_k(const float* __restrict__ partials, float* __restrict__ stats,
                           int nblk)
{
    int grp = blockIdx.x, t = threadIdx.x;
    float s = 0.f, ss = 0.f;
    for (int i = t; i < nblk; i += 64) {
        s  += partials[(grp * nblk + i) * 2];
        ss += partials[(grp * nblk + i) * 2 + 1];
    }
    for (int off = 1; off < 64; off <<= 1) { s += __shfl_xor(s, off); ss += __shfl_xor(ss, off); }
    if (t == 0) {
        const float N = 524288.0f;
        float mu = s / N;
        float var = ss / N - mu * mu;
        stats[grp * 2]     = mu;
        stats[grp * 2 + 1] = 1.0f / sqrtf(var + 0.001f);
    }
}

// ---------------------------------------------------------------------------
// Wvf = Wv @ Wfc  (128x128). grid=32 blocks x 256 threads (4 rows/block).
// ---------------------------------------------------------------------------
__global__ __launch_bounds__(256) void wvf_prep_k(const float* __restrict__ Wv,
                                                  const float* __restrict__ Wfc,
                                                  float* __restrict__ out)
{
    int t = threadIdx.x;
    int rr = t >> 6, cl = t & 63;
    int r = blockIdx.x * 4 + rr;
    float a0 = 0.f, a1 = 0.f;
    for (int k = 0; k < 128; k++) {
        float wv = Wv[r * 128 + k];
        a0 = fmaf(wv, Wfc[k * 128 + cl], a0);
        a1 = fmaf(wv, Wfc[k * 128 + 64 + cl], a1);
    }
    out[r * 128 + cl] = a0;
    out[r * 128 + 64 + cl] = a1;
}

// ---------------------------------------------------------------------------
// C[M,128] = act( gn(X) @ W + bias ), M=131072.
// grid=1024 (128 rows/block), block=128, per-thread 8x16 tile.
// cols of thread = cg*4 + 32m (m=0..3)  -> conflict-free b128 B reads.
// sA stored transposed [k][row] stride 132; sB [k][col] stride 132.
// Optional fused group-stats output (for qraw: bias=null, leaky=0).
// ---------------------------------------------------------------------------
__global__ __launch_bounds__(128, 2) void gemm128_v2(const float* __restrict__ X,
                                                     const float* __restrict__ W,
                                                     const float* __restrict__ bias,
                                                     const float* __restrict__ stats,
                                                     float* __restrict__ C, int leaky,
                                                     float* __restrict__ statsout)
{
    __shared__ float sA[32 * 132];
    __shared__ float sB[32 * 132];
    __shared__ float sRed[128 * 8];
    int t = threadIdx.x;
    long row0 = (long)blockIdx.x * 128;
    int bidx = (int)(row0 >> 14);

    float muv[4], rsv[4];
#pragma unroll
    for (int g = 0; g < 4; g++) {
        muv[g] = stats ? stats[(bidx * 4 + g) * 2]     : 0.f;
        rsv[g] = stats ? stats[(bidx * 4 + g) * 2 + 1] : 1.f;
    }
    int rg = t >> 3, cg = t & 7;
    float acc[8][16];
#pragma unroll
    for (int i = 0; i < 8; i++)
#pragma unroll
        for (int j = 0; j < 16; j++) acc[i][j] = 0.f;

    const float* xs = X + (row0 + t) * 128;
    int kb = t >> 2, c0 = (t & 3) * 32;

    for (int kt = 0; kt < 4; kt++) {
        // stage A transposed + normalized (k-range [32kt,32kt+32) == group kt)
        float mu = muv[kt], rs = rsv[kt];
        const float* asrc = xs + kt * 32;
#pragma unroll
        for (int q = 0; q < 8; q++) {
            float4 v = *(const float4*)(asrc + 4 * q);
            sA[(4 * q + 0) * 132 + t] = (v.x - mu) * rs;
            sA[(4 * q + 1) * 132 + t] = (v.y - mu) * rs;
            sA[(4 * q + 2) * 132 + t] = (v.z - mu) * rs;
            sA[(4 * q + 3) * 132 + t] = (v.w - mu) * rs;
        }
        // stage B
        const float* bsrc = W + (long)(kt * 32 + kb) * 128 + c0;
#pragma unroll
        for (int q = 0; q < 8; q++)
            *(float4*)&sB[kb * 132 + c0 + 4 * q] = *(const float4*)(bsrc + 4 * q);
        __syncthreads();
#pragma unroll 4
        for (int k = 0; k < 32; k++) {
            float4 a0 = *(const float4*)&sA[k * 132 + rg * 8];
            float4 a1 = *(const float4*)&sA[k * 132 + rg * 8 + 4];
            float b[16];
#pragma unroll
            for (int m = 0; m < 4; m++) {
                float4 bv = *(const float4*)&sB[k * 132 + cg * 4 + 32 * m];
                b[m * 4 + 0] = bv.x; b[m * 4 + 1] = bv.y;
                b[m * 4 + 2] = bv.z; b[m * 4 + 3] = bv.w;
            }
            float a[8] = {a0.x, a0.y, a0.z, a0.w, a1.x, a1.y, a1.z, a1.w};
#pragma unroll
            for (int i = 0; i < 8; i++)
#pragma unroll
                for (int j = 0; j < 16; j++)
                    acc[i][j] = fmaf(a[i], b[j], acc[i][j]);
        }
        __syncthreads();
    }

    float bv16[16];
#pragma unroll
    for (int m = 0; m < 4; m++)
#pragma unroll
        for (int j = 0; j < 4; j++)
            bv16[m * 4 + j] = bias ? bias[cg * 4 + 32 * m + j] : 0.f;
#pragma unroll
    for (int i = 0; i < 8; i++) {
        long r = row0 + rg * 8 + i;
#pragma unroll
        for (int m = 0; m < 4; m++) {
            float4 o;
            o.x = acc[i][m * 4 + 0] + bv16[m * 4 + 0];
            o.y = acc[i][m * 4 + 1] + bv16[m * 4 + 1];
            o.z = acc[i][m * 4 + 2] + bv16[m * 4 + 2];
            o.w = acc[i][m * 4 + 3] + bv16[m * 4 + 3];
            if (leaky) {
                o.x = (o.x >= 0.f) ? o.x : 0.01f * o.x;
                o.y = (o.y >= 0.f) ? o.y : 0.01f * o.y;
                o.z = (o.z >= 0.f) ? o.z : 0.01f * o.z;
                o.w = (o.w >= 0.f) ? o.w : 0.01f * o.w;
            }
            *(float4*)(C + r * 128 + cg * 4 + 32 * m) = o;
        }
    }
    if (statsout) {
        // bias==null && leaky==0 on this path, so stored value == acc
        float s[4] = {0.f, 0.f, 0.f, 0.f}, ss[4] = {0.f, 0.f, 0.f, 0.f};
#pragma unroll
        for (int i = 0; i < 8; i++)
#pragma unroll
            for (int m = 0; m < 4; m++)
#pragma unroll
                for (int j = 0; j < 4; j++) {
                    float v = acc[i][m * 4 + j];
                    s[m] += v; ss[m] += v * v;
                }
#pragma unroll
        for (int m = 0; m < 4; m++) {
            sRed[t * 8 + 2 * m]     = s[m];
            sRed[t * 8 + 2 * m + 1] = ss[m];
        }
        __syncthreads();
        if (t < 8) {
            int g = t >> 1, which = t & 1;
            float a2 = 0.f;
            for (int u = 0; u < 128; u++) a2 += sRed[u * 8 + 2 * g + which];
            statsout[((bidx * 4 + g) * 128 + (int)(blockIdx.x & 127)) * 2 + which] = a2;
        }
    }
}

// ---------------------------------------------------------------------------
// attn: q = gn2(qraw) -> outQ; S = sq_dist(q,q); softmax; min-max -> af
// grid=1024 (2 windows/block), block=256 (128 threads/window, 8x4 tiles).
// sQ XOR-swizzled for conflict-free b128; S aliased into sQ after QK.
// ---------------------------------------------------------------------------
__global__ __launch_bounds__(256, 2) void attn_v2(const float* __restrict__ Qraw,
                                                  const float* __restrict__ stats,
                                                  float* __restrict__ outQ,
                                                  float* __restrict__ outAF)
{
    __shared__ float sQ[2][8192];
    __shared__ float sN[2][64];
    int t = threadIdx.x;
    int wl = t >> 7;               // window half
    int tl = t & 127;
    int w = blockIdx.x * 2 + wl;
    int bidx = w >> 8;
    float muv[4], rsv[4];
#pragma unroll
    for (int g = 0; g < 4; g++) {
        muv[g] = stats[(bidx * 4 + g) * 2];
        rsv[g] = stats[(bidx * 4 + g) * 2 + 1];
    }
    // stage (normalize, write q out, swizzled LDS write)
    {
        int r = tl >> 1, q0 = (tl & 1) * 16;
        int sw = r >> 3;
        const float* src = Qraw + (long)w * 8192 + r * 128 + q0 * 4;
        float* dstG = outQ + (long)w * 8192 + r * 128 + q0 * 4;
#pragma unroll
        for (int q = 0; q < 16; q++) {
            float4 v = *(const float4*)(src + 4 * q);
            int g = (q0 + q) >> 3;
            float mu = muv[g], rs = rsv[g];
            v.x = (v.x - mu) * rs; v.y = (v.y - mu) * rs;
            v.z = (v.z - mu) * rs; v.w = (v.w - mu) * rs;
            *(float4*)(dstG + 4 * q) = v;
            *(float4*)&sQ[wl][r * 128 + 4 * ((q0 + q) ^ sw)] = v;
        }
    }
    __syncthreads();
    if (tl < 64) {
        int r = tl, sw = r >> 3;
        float s = 0.f;
#pragma unroll
        for (int q = 0; q < 32; q++) {
            float4 v = *(const float4*)&sQ[wl][r * 128 + 4 * (q ^ sw)];
            s += v.x * v.x + v.y * v.y + v.z * v.z + v.w * v.w;
        }
        sN[wl][r] = s;
    }
    __syncthreads();
    // QK: rows ty*8+i, cols tx*4+bb
    int ty = tl >> 4, tx = tl & 15;
    float acc[8][4];
#pragma unroll
    for (int i = 0; i < 8; i++)
#pragma unroll
        for (int bb = 0; bb < 4; bb++) acc[i][bb] = 0.f;
    for (int kq = 0; kq < 32; kq++) {
        float4 bf[4];
#pragma unroll
        for (int bb = 0; bb < 4; bb++) {
            int col = tx * 4 + bb;
            bf[bb] = *(const float4*)&sQ[wl][col * 128 + 4 * (kq ^ (col >> 3))];
        }
#pragma unroll
        for (int i = 0; i < 8; i++) {
            int row = ty * 8 + i;
            float4 av = *(const float4*)&sQ[wl][row * 128 + 4 * (kq ^ (row >> 3))];
#pragma unroll
            for (int bb = 0; bb < 4; bb++)
                acc[i][bb] += av.x * bf[bb].x + av.y * bf[bb].y
                            + av.z * bf[bb].z + av.w * bf[bb].w;
        }
    }
    __syncthreads();                 // done reading sQ
    float* sS = &sQ[wl][0];          // alias, stride 65
#pragma unroll
    for (int i = 0; i < 8; i++) {
        int row = ty * 8 + i;
#pragma unroll
        for (int bb = 0; bb < 4; bb++) {
            int col = tx * 4 + bb;
            sS[row * 65 + col] = sN[wl][row] + sN[wl][col] - 2.f * acc[i][bb];
        }
    }
    __syncthreads();
    // epilogue: lane = row, serial over j (no shuffles)
    if (tl < 64) {
        int r = tl;
        float mnS = sS[r * 65];
        for (int j = 1; j < 64; j++) mnS = fminf(mnS, sS[r * 65 + j]);
        float sum = 0.f, pmx = -1.f, pmn = 1e30f;
        for (int j = 0; j < 64; j++) {
            float p = expf(-SCL_F * (sS[r * 65 + j] - mnS));
            sS[r * 65 + j] = p;
            sum += p;
            pmx = fmaxf(pmx, p);
            pmn = fminf(pmn, p);
        }
        float rsum = 1.0f / sum;
        float amn = pmn * rsum, amx = pmx * rsum;
        float dinv = 1.0f / (amx - amn + 1e-8f);
        float* dst = outAF + (long)w * 4096 + r * 64;
        for (int j = 0; j < 64; j += 4) {
            float4 o;
            o.x = (sS[r * 65 + j + 0] * rsum - amn) * dinv;
            o.y = (sS[r * 65 + j + 1] * rsum - amn) * dinv;
            o.z = (sS[r * 65 + j + 2] * rsum - amn) * dinv;
            o.w = (sS[r * 65 + j + 3] * rsum - amn) * dinv;
            *(float4*)(dst + j) = o;
        }
    }
}

// ---------------------------------------------------------------------------
// Per-window clustering, register/readlane rewrite (DS-minimized).
// lane = row q; wave wv owns k = 4kk+wv (registers dk,ak,T[16]).
// Pair sum via min-identity; j<k handled by quad decomposition with
// wave-uniform branches. grid=2048, block=256.
// ---------------------------------------------------------------------------
__global__ __launch_bounds__(256, 4) void cluster_v3(const float* __restrict__ AF,
                                                     const float* __restrict__ GEO,
                                                     float* __restrict__ oCLM,
                                                     float* __restrict__ oCLR,
                                                     float* __restrict__ oCOMP,
                                                     float* __restrict__ oGEO,
                                                     float* __restrict__ oSCM,
                                                     float* __restrict__ wCLMM)
{
    __shared__ float sAF[64 * 65];
    __shared__ float sPart[4 * 64 * 3];
    __shared__ float sCLM[8 * 65];
    int t = threadIdx.x, w = blockIdx.x;
    int wv = t >> 6, lane = t & 63;
    const float* afw = AF + (long)w * 4096;
#pragma unroll
    for (int i = 0; i < 4; i++) {
        int f4 = i * 256 + t;
        float4 v = *(const float4*)(afw + f4 * 4);
        int r = f4 >> 4, c4 = (f4 & 15) * 4;
        float* dst = &sAF[r * 65 + c4];
        dst[0] = fminf(fmaxf(v.x, 1e-5f), 0.99999f);
        dst[1] = fminf(fmaxf(v.y, 1e-5f), 0.99999f);
        dst[2] = fminf(fmaxf(v.z, 1e-5f), 0.99999f);
        dst[3] = fminf(fmaxf(v.w, 1e-5f), 0.99999f);
    }
    // per-lane geo row (lane = element index)
    const float* gp = GEO + ((long)w * 64 + lane) * 6;
    float2 g01 = *(const float2*)(gp);
    float2 g23 = *(const float2*)(gp + 2);
    float2 g45 = *(const float2*)(gp + 4);
    float gD = g01.x, gA = g23.x, gI = g23.y, gX = g45.x, gY = g45.y;
    __syncthreads();

    // ---- phase 1 ----
    const float* afrow = &sAF[lane * 65];
    float dk[16], ak[16], T[16];
    float v0 = 0.f, v1 = 0.f;
#pragma unroll
    for (int kk = 0; kk < 16; kk++) {
        int kc = kk * 4 + wv;
        float afk = afrow[kc];
        float d = afk * rlane(gD, kc);
        float a = afk * rlane(gA, kc);
        dk[kk] = d; ak[kk] = a; T[kk] = 0.f;
        float m = d * a;
        float dx = gX - rlane(gX, kc), dy = gY - rlane(gY, kc);
        v0 += d * rlane(gI, kc) + m * (dx * dx + dy * dy);
        v1 += m * a;
    }
    for (int jq = 0; jq < 16; jq++) {
        float dj[4], aj[4];
#pragma unroll
        for (int jr = 0; jr < 4; jr++) {
            int j = jq * 4 + jr;
            float afj = afrow[j];
            dj[jr] = afj * rlane(gD, j);
            aj[jr] = afj * rlane(gA, j);
        }
#pragma unroll
        for (int kk = 0; kk < 16; kk++) {
            if (kk > jq) {
#pragma unroll
                for (int jr = 0; jr < 4; jr++)
                    T[kk] = fmaf(aj[jr], fminf(dj[jr], dk[kk]), T[kk]);
            } else if (kk == jq) {
                if (0 < wv) T[kk] = fmaf(aj[0], fminf(dj[0], dk[kk]), T[kk]);
                if (1 < wv) T[kk] = fmaf(aj[1], fminf(dj[1], dk[kk]), T[kk]);
                if (2 < wv) T[kk] = fmaf(aj[2], fminf(dj[2], dk[kk]), T[kk]);
            }
        }
    }
    float S = 0.f;
#pragma unroll
    for (int kk = 0; kk < 16; kk++) S = fmaf(ak[kk], T[kk], S);
    {
        float* p = &sPart[(wv * 64 + lane) * 3];
        p[0] = v0; p[1] = v1; p[2] = S;
    }
    __syncthreads();

    // ---- combine + greedy selection (wave 0) ----
    if (t < 64) {
        int k = lane;
        float c0 = 0.f, c1 = 0.f, c2 = 0.f;
#pragma unroll
        for (int u = 0; u < 4; u++) {
            const float* p = &sPart[(u * 64 + k) * 3];
            c0 += p[0]; c1 += p[1]; c2 += p[2];
        }
        float compk = ((c1 + 2.f * c2) / TWO_PI_F) / c0;
        float sc = 1.0f;
        for (int c = 0; c < 7; c++) {
            float score = compk * sc;
            float mx = score;
            for (int off = 1; off < 64; off <<= 1) mx = fmaxf(mx, __shfl_xor(mx, off));
            unsigned long long bl = __ballot(score == mx);
            int idx = __ffsll(bl) - 1;
            float rowk = sAF[idx * 65 + k];
            float clm = sc * rowk;
            sCLM[c * 65 + k] = clm;
            oCLM[(long)w * 512 + c * 64 + k] = clm;
            if (k == 0) oCLR[(long)w * 7 + c] = (float)idx;
            sc *= (1.0f - rowk);
        }
        sCLM[7 * 65 + k] = sc;
        oCLM[(long)w * 512 + 448 + k] = sc;
        oSCM[(long)w * 64 + k] = sc;
    }
    __syncthreads();

    // ---- phase 3: cluster aggregates + second compactness (2 clusters/wave) ----
    {
        int k = lane;
        for (int cc = 0; cc < 2; cc++) {
            int c = wv + cc * 4;
            float clm = sCLM[c * 65 + k];
            float cd = clm * gD, ca = clm * gA;
            float cm = cd * ca;
            float T3 = 0.f;
            for (int j = 0; j < 64; j++)
                T3 = fmaf(rlane(ca, j), fminf(rlane(cd, j), cd), T3);
            float r0 = cm, r1 = ca, r2c = cm * gX, r3 = cm * gY, r4 = clm;
            float r5 = cm * ca;
            float r6 = ca * T3 - ca * ca * cd;   // 2*S contribution (self removed)
            for (int off = 1; off < 64; off <<= 1) {
                r0 += __shfl_xor(r0, off); r1 += __shfl_xor(r1, off);
                r2c += __shfl_xor(r2c, off); r3 += __shfl_xor(r3, off);
                r4 += __shfl_xor(r4, off); r5 += __shfl_xor(r5, off);
                r6 += __shfl_xor(r6, off);
            }
            float mass = r0, area = r1;
            float qx = r2c / (mass + 1e-8f), qy = r3 / (mass + 1e-8f);
            wCLMM[(long)w * 512 + c * 64 + k] = clm / (r4 + 1e-8f);
            float dx = qx - gX, dy = qy - gY;
            float w0v = cd * gI + cm * (dx * dx + dy * dy);
            for (int off = 1; off < 64; off <<= 1) w0v += __shfl_xor(w0v, off);
            if (k == 0) {
                oCOMP[(long)w * 8 + c] = ((r5 + r6) / TWO_PI_F) / w0v;
                float* og = oGEO + (long)w * 48 + c * 6;
                og[0] = mass / (area + 1e-8f); og[1] = mass; og[2] = area;
                og[3] = w0v; og[4] = qx; og[5] = qy;
            }
        }
    }
}

// ---------------------------------------------------------------------------
// cl_f = t1*sigma + sc*(mu+b2) + bfc + u@W2 + t1@Wvf   (Wvf = Wv@Wfc)
//   u = mm@h1, t1 = mm@_fn. readlane-based GEMVs. grid=2048, block=256.
// Waves: 0/1 -> u (ch half 0/1); 2/3 -> t1. Stage2: 0/1 -> W2; 2/3 -> Wvf.
// ---------------------------------------------------------------------------
__global__ __launch_bounds__(256, 4) void final_v2(const float* __restrict__ inF,
                                                   const float* __restrict__ H1,
                                                   const float* __restrict__ CLMM,
                                                   const float* __restrict__ stats1,
                                                   const float* __restrict__ W2,
                                                   const float* __restrict__ b2,
                                                   const float* __restrict__ Wvf,
                                                   const float* __restrict__ bfc,
                                                   float* __restrict__ oCLF)
{
    __shared__ float sH[64 * 128];
    __shared__ float sF[64 * 128];
    __shared__ float sU[8 * 129];
    __shared__ float sT[8 * 129];
    int t = threadIdx.x, w = blockIdx.x;
    int bidx = w >> 8;
    int wv = t >> 6, lane = t & 63;

    float mmL[8];
#pragma unroll
    for (int c = 0; c < 8; c++)
        mmL[c] = CLMM[(long)w * 512 + c * 64 + lane];

    float muv[4], rsv[4];
#pragma unroll
    for (int g = 0; g < 4; g++) {
        muv[g] = stats1[(bidx * 4 + g) * 2];
        rsv[g] = stats1[(bidx * 4 + g) * 2 + 1];
    }
    // stage h1 and normalized in_f
    {
        int r = t >> 2, q0 = (t & 3) * 8;
        const float* hs = H1 + (long)w * 8192 + r * 128 + q0 * 4;
        const float* fs = inF + (long)w * 8192 + r * 128 + q0 * 4;
#pragma unroll
        for (int q = 0; q < 8; q++) {
            float4 hv = *(const float4*)(hs + 4 * q);
            *(float4*)&sH[r * 128 + (q0 + q) * 4] = hv;
            float4 fv = *(const float4*)(fs + 4 * q);
            int g = (q0 + q) >> 3;
            float mu = muv[g], rs = rsv[g];
            fv.x = (fv.x - mu) * rs; fv.y = (fv.y - mu) * rs;
            fv.z = (fv.z - mu) * rs; fv.w = (fv.w - mu) * rs;
            *(float4*)&sF[r * 128 + (q0 + q) * 4] = fv;
        }
    }
    __syncthreads();
    // stage 1: K=64 GEMVs
    int ch = lane + 64 * (wv & 1);
    {
        const float* src = (wv < 2) ? sH : sF;
        float acc1[8];
#pragma unroll
        for (int c = 0; c < 8; c++) acc1[c] = 0.f;
        for (int j = 0; j < 64; j++) {
            float f = src[j * 128 + ch];
#pragma unroll
            for (int c = 0; c < 8; c++)
                acc1[c] = fmaf(rlane(mmL[c], j), f, acc1[c]);
        }
        float* dst1 = (wv < 2) ? sU : sT;
#pragma unroll
        for (int c = 0; c < 8; c++) dst1[c * 129 + ch] = acc1[c];
    }
    __syncthreads();
    // stage 2: K=128 GEMVs with global weights
    float xL0[8], xL1[8];
    {
        const float* s2 = (wv < 2) ? sU : sT;
#pragma unroll
        for (int c = 0; c < 8; c++) {
            xL0[c] = s2[c * 129 + lane];
            xL1[c] = s2[c * 129 + 64 + lane];
        }
    }
    const float* Wm = (wv < 2) ? W2 : Wvf;
    float acc2[8];
#pragma unroll
    for (int c = 0; c < 8; c++) acc2[c] = 0.f;
    for (int k = 0; k < 64; k++) {
        float wk = Wm[k * 128 + ch];
#pragma unroll
        for (int c = 0; c < 8; c++)
            acc2[c] = fmaf(rlane(xL0[c], k), wk, acc2[c]);
    }
    for (int k = 0; k < 64; k++) {
        float wk = Wm[(k + 64) * 128 + ch];
#pragma unroll
        for (int c = 0; c < 8; c++)
            acc2[c] = fmaf(rlane(xL1[c], k), wk, acc2[c]);
    }
    if (wv >= 2) {
        // + t1 * sigma  (t1[c][ch] is this lane's own value)
        float sig = 1.0f / rsv[ch >> 5];
#pragma unroll
        for (int c = 0; c < 8; c++) {
            float t1ch = (wv & 1) ? xL1[c] : xL0[c];
            acc2[c] = fmaf(t1ch, sig, acc2[c]);
        }
    }
    __syncthreads();
    float* sP = sH;   // reuse
    if (wv >= 2) {
#pragma unroll
        for (int c = 0; c < 8; c++) sP[c * 129 + ch] = acc2[c];
    }
    __syncthreads();
    if (wv < 2) {
        float scv[8];
#pragma unroll
        for (int c = 0; c < 8; c++) {
            float s = mmL[c];
            for (int off = 1; off < 64; off <<= 1) s += __shfl_xor(s, off);
            scv[c] = s;
        }
        float mub = muv[ch >> 5] + b2[ch];
        float bfv = bfc[ch];
#pragma unroll
        for (int c = 0; c < 8; c++) {
            float o = acc2[c] + sP[c * 129 + ch] + scv[c] * mub + bfv;
            oCLF[(long)w * 1024 + c * 128 + ch] = o;
        }
    }
}

// ---------------------------------------------------------------------------
extern "C" void kernel_launch(void* const* d_in, const int* in_sizes, int n_in,
                              void* d_out, int out_size, void* d_ws, size_t ws_size,
                              hipStream_t stream)
{
    (void)in_sizes; (void)n_in; (void)out_size; (void)ws_size;
    const float* in_f   = (const float*)d_in[0];
    const float* in_geo = (const float*)d_in[1];
    const float* W1  = (const float*)d_in[2];
    const float* b1  = (const float*)d_in[3];
    const float* W2  = (const float*)d_in[4];
    const float* b2  = (const float*)d_in[5];
    const float* Wfc = (const float*)d_in[6];
    const float* bfc = (const float*)d_in[7];
    const float* Wq  = (const float*)d_in[8];
    const float* Wv  = (const float*)d_in[9];
    float* out = (float*)d_out;
    float* ws  = (float*)d_ws;

    // workspace (floats)
    float* qh     = ws;                    // 16,777,216 (qraw then h1)
    float* clmm   = ws + 16777216;         //  1,048,576
    float* stats1 = ws + 17825792;         //  64
    float* stats2 = ws + 17825856;         //  64
    float* wvf    = ws + 17825920;         //  16,384
    float* part   = ws + 17842304;         //  8,192

    // output layout (floats)
    float* o_clf  = out;                   // (8,256,8,128)
    float* o_clm  = out + 2097152;         // (8,256,8,64)
    float* o_geo  = out + 3145728;         // (8,256,8,6)
    float* o_clr  = out + 3244032;         // (8,256,7,1)
    float* o_comp = out + 3258368;         // (8,256,8,1)
    float* o_af   = out + 3274752;         // (8,256,64,64)
    float* o_scm  = out + 11663360;        // (8,256,1,64)
    float* o_q    = out + 11794432;        // (8,256,64,128)

    gn_partial_k<<<dim3(64, 32), 256, 0, stream>>>(in_f, part);
    gn_final_k<<<32, 64, 0, stream>>>(part, stats1, 64);
    wvf_prep_k<<<32, 256, 0, stream>>>(Wv, Wfc, wvf);
    // qraw = gn1(in_f) @ Wq, fused stats2 partials
    gemm128_v2<<<1024, 128, 0, stream>>>(in_f, Wq, nullptr, stats1, qh, 0, part);
    gn_final_k<<<32, 64, 0, stream>>>(part, stats2, 128);
    attn_v2<<<1024, 256, 0, stream>>>(qh, stats2, o_q, o_af);
    // h1 = leaky(gn1(in_f) @ W1 + b1) (reuses qraw buffer)
    gemm128_v2<<<1024, 128, 0, stream>>>(in_f, W1, b1, stats1, qh, 1, nullptr);
    cluster_v3<<<2048, 256, 0, stream>>>(o_af, in_geo, o_clm, o_clr, o_comp, o_geo,
                                         o_scm, clmm);
    final_v2<<<2048, 256, 0, stream>>>(in_f, qh, clmm, stats1, W2, b2, wvf, bfc, o_clf);
}